// Round 4
// baseline (2213.281 us; speedup 1.0000x reference)
//
#include <hip/hip_runtime.h>
#include <hip/hip_bf16.h>

// Problem constants (fixed by reference)
#define NN 4096      // nodes
#define EE 16384     // edges
#define GG 128       // graphs
#define EDIM 16      // edge_dim
#define HD 4096      // edge-MLP width = 64*64

// Factorized-algorithm tiling (R3: 32-node groups, 4-wave blocks, 2 blocks/CU,
// kk-pair per wave, conflict-free XOR sY layout, strict post-barrier prefetch)
#define NGROUPS 128      // node groups (32 nodes each)
#define GK 8             // k-chunks (one 4MB W2q slice per XCD)
#define KSUBS 64         // 8-k sub-iterations per block
#define MAXT 24          // max 16-slot edge tiles per group (avg ~10)
#define MAXSLOT (MAXT * 16)
#define MAXTW 6          // max tiles per wave (4 waves)
#define SYU 16384        // shorts per sY buffer: 32 rows x 64 cols x 8 shorts = 32KB
#define PANEL (8 * 64 * 64)   // W2q shorts per su

typedef __attribute__((ext_vector_type(8))) short short8;
typedef __attribute__((ext_vector_type(4))) float float4v;

static __device__ inline unsigned short f2b(float f) {
    unsigned u = __float_as_uint(f);
    unsigned r = u + 0x7fff + ((u >> 16) & 1);   // RNE
    return (unsigned short)(r >> 16);
}

static __device__ inline unsigned pk2(float a, float b) {
    __hip_bfloat162 p = __float22bfloat162_rn(make_float2(a, b));
    return *(unsigned*)&p;
}

// ---------------------------------------------------------------------------
// h = relu(ea @ w1 + b1) -> bf16 [EE][HD]   (row EE of hB is a zero row,
// memset once per launch, used as the target of empty-slot gathers)
// ---------------------------------------------------------------------------
__global__ void hker(const float* __restrict__ ea, const float* __restrict__ w1,
                     const float* __restrict__ b1, unsigned short* __restrict__ hB) {
    __shared__ float sea[16 * 16];
    const int tid = threadIdx.x;
    const int j = blockIdx.x * 256 + tid;
    const int e0 = blockIdx.y * 16;
    float w[16];
#pragma unroll
    for (int k = 0; k < 16; ++k) w[k] = w1[k * HD + j];
    const float b = b1[j];
    sea[tid] = ea[e0 * EDIM + tid];
    __syncthreads();
#pragma unroll 4
    for (int el = 0; el < 16; ++el) {
        float a = b;
#pragma unroll
        for (int k = 0; k < 16; ++k) a += sea[el * 16 + k] * w[k];
        hB[(size_t)(e0 + el) * HD + j] = f2b(fmaxf(a, 0.f));
    }
}

// ---------------------------------------------------------------------------
// W2q permute, su-contiguous per (reader-wave, lane):
//   W2q[ ((ss*8 + kk)*64 + lane)*64 + (tt*2+q2)*8 + t ]
//     = bf16( w2[k*HD + (q2*32+quad*8+t)*64 + o] )   with k = ss*8+kk,
//       lane = quad*16+lm, o = tt*16+lm.
// ---------------------------------------------------------------------------
__global__ void wperm(const float* __restrict__ w2, unsigned short* __restrict__ W2q) {
    __shared__ float t[64 * 65];
    const int k = blockIdx.x;
    const int tid = threadIdx.x;
    const int o = tid & 63, r4 = tid >> 6;
#pragma unroll
    for (int it = 0; it < 16; ++it) {
        int i = it * 4 + r4;
        t[i * 65 + o] = w2[(size_t)k * HD + i * 64 + o];
    }
    __syncthreads();
    const int o2 = tid >> 2, q = tid & 3;
    const int q2 = q >> 1;
    const int j0 = (o2 >> 4) * 2 + q2;     // fragment slot j = tt*2+q2
    const int lmm = o2 & 15;
    const int blk = k;                      // = ss*8 + kk
#pragma unroll
    for (int cc = 0; cc < 2; ++cc) {
        const int quad = (q & 1) * 2 + cc;
        const int ib = q * 16 + cc * 8;     // i-base = q2*32 + quad*8
        size_t base = ((size_t)(blk * 64 + quad * 16 + lmm)) * 64 + j0 * 8;
        unsigned b0 = pk2(t[(ib + 0) * 65 + o2], t[(ib + 1) * 65 + o2]);
        unsigned b1 = pk2(t[(ib + 2) * 65 + o2], t[(ib + 3) * 65 + o2]);
        unsigned b2_ = pk2(t[(ib + 4) * 65 + o2], t[(ib + 5) * 65 + o2]);
        unsigned b3 = pk2(t[(ib + 6) * 65 + o2], t[(ib + 7) * 65 + o2]);
        *(uint4*)(&W2q[base]) = make_uint4(b0, b1, b2_, b3);
    }
}

// ---------------------------------------------------------------------------
// Edge bucketing (structure fixed per launch; rebuilt every call)
// ---------------------------------------------------------------------------
__global__ void count_edges(const int* __restrict__ src, const int* __restrict__ dst,
                            int* __restrict__ cnt_src, float* __restrict__ cnt_dst) {
    const int e = blockIdx.x * 256 + threadIdx.x;
    atomicAdd(&cnt_src[src[e]], 1);
    atomicAdd(&cnt_dst[dst[e]], 1.f);
}

__global__ void build_layout(const int* __restrict__ cnt_src, int* __restrict__ node_slot_base,
                             int* __restrict__ tile_cluster, int* __restrict__ group_ntiles) {
    const int g = threadIdx.x;        // 0..127, 32-node groups
    int nt = 0;
    int slot = g * MAXSLOT;
    for (int c = 0; c < 8; ++c) {     // 8 clusters of 4 nodes
        int d = 0;
        for (int j = 0; j < 4; ++j) {
            int n = g * 32 + c * 4 + j;
            node_slot_base[n] = slot + d;
            d += cnt_src[n];
        }
        int tcnt = (d + 15) >> 4;
        if (nt + tcnt > MAXT) tcnt = MAXT - nt;   // safety clamp
        for (int j = 0; j < tcnt; ++j) tile_cluster[g * MAXT + nt + j] = c;
        nt += tcnt;
        slot += tcnt * 16;
    }
    group_ntiles[g] = nt;
}

__global__ void fill_slots(const int* __restrict__ src, const int* __restrict__ dst,
                           int* __restrict__ fill, const int* __restrict__ node_slot_base,
                           int* __restrict__ slot_info) {
    const int e = blockIdx.x * 256 + threadIdx.x;
    const int n = src[e];
    const int pos = atomicAdd(&fill[n], 1);
    const int s = node_slot_base[n] + pos;
    const int g = n >> 5;             // 32 nodes/group
    if (s < g * MAXSLOT + MAXSLOT)
        slot_info[s] = e | ((n & 3) << 14) | (dst[e] << 16);
}

// ---------------------------------------------------------------------------
// xb[n,o] = sum_i x[n,i]*b2[i*64+o]; then scatter to agg (bias term of theta)
// ---------------------------------------------------------------------------
__global__ void xb_ker(const float* __restrict__ xcur, const float* __restrict__ b2,
                       float* __restrict__ xb) {
    const int n = blockIdx.x * 4 + (threadIdx.x >> 6);
    const int o = threadIdx.x & 63;
    float a = 0.f;
#pragma unroll
    for (int i = 0; i < 64; ++i) a += xcur[n * 64 + i] * b2[i * 64 + o];
    xb[n * 64 + o] = a;
}

__global__ void b2scatter(const float* __restrict__ xb, const int* __restrict__ src,
                          const int* __restrict__ dst, float* __restrict__ agg) {
    const int e = blockIdx.x * 4 + (threadIdx.x >> 6);
    const int o = threadIdx.x & 63;
    atomicAdd(&agg[(size_t)dst[e] * 64 + o], xb[(size_t)src[e] * 64 + o]);
}

// ---------------------------------------------------------------------------
// Fused factorized kernel — 4-wave blocks, 32-node groups, 2 blocks/CU.
//   Each wave computes kk = 2*wave and 2*wave+1 -> writes COMPLETE 16B sY
//   units via ds_write_b128. sY layout: unit U(row,col) = col*32 + (row ^
//   (col&7)); analytically conflict-free (8 lanes per bank-group) on both
//   the b128 writes and the b128 reads. One barrier per su; ALL global
//   prefetches (W2q bf reload in place, hB hd A/B) issued strictly AFTER
//   the barrier so the vmcnt(0) barrier-drain never waits on them.
// ---------------------------------------------------------------------------
__global__ __launch_bounds__(256, 2)
void ygemm_msg(const float* __restrict__ xcur, const unsigned short* __restrict__ hB,
               const unsigned short* __restrict__ W2q, const int* __restrict__ slot_info,
               const int* __restrict__ tile_cluster, const int* __restrict__ group_ntiles,
               float* __restrict__ agg) {
    __shared__ __align__(16) unsigned short sA[32 * 72];     // 4.5 KB
    __shared__ __align__(16) unsigned short sY[2 * SYU];     // 64 KB double buffer

    const int bid = blockIdx.x;
    const int g = bid >> 3;
    const int kc = bid & 7;
    const int tid = threadIdx.x;
    const int lane = tid & 63, wave = tid >> 6;    // wave 0..3
    const int quad = lane >> 4, lm = lane & 15;

    // stage x group (32 nodes x 64 i) as bf16
    {
        const int n = tid >> 3, ib = (tid & 7) * 8;
        const float* xp = xcur + (size_t)(g * 32 + n) * 64 + ib;
        uint4 w = make_uint4(pk2(xp[0], xp[1]), pk2(xp[2], xp[3]),
                             pk2(xp[4], xp[5]), pk2(xp[6], xp[7]));
        *(uint4*)(&sA[n * 72 + ib]) = w;
    }

    const int ntiles = group_ntiles[g];
    int infoR[MAXTW], voff[MAXTW], rbase[MAXTW];
    unsigned shl5[MAXTW];
#pragma unroll
    for (int ai = 0; ai < MAXTW; ++ai) {
        const int ti = wave + ai * 4;
        const int info = (ti < ntiles) ? slot_info[g * MAXSLOT + ti * 16 + lm] : -1;
        const int tc   = (ti < ntiles) ? tile_cluster[g * MAXT + ti] : 0;
        infoR[ai] = info;
        voff[ai]  = ((info >= 0) ? (info & 0x3FFF) : EE) * HD + quad * 2;
        rbase[ai] = lm * 256 + (((tc * 4 + quad) ^ (lm & 7)) << 3);   // shorts
        shl5[ai]  = (unsigned)(((info >> 14) & 3) * 16);
    }

    float4v acc2[MAXTW][4];
#pragma unroll
    for (int a = 0; a < MAXTW; ++a)
#pragma unroll
        for (int t = 0; t < 4; ++t) {
            acc2[a][t][0] = 0.f; acc2[a][t][1] = 0.f;
            acc2[a][t][2] = 0.f; acc2[a][t][3] = 0.f;
        }

    // phase-1 write base (shorts): full-unit b128 writes, rows s*16 + ((quad*4+wave)^(lm&7))
    const int wb0 = lm * 256 + (((quad * 4 + wave) ^ (lm & 7)) << 3);
    __syncthreads();

    // loop-invariant A-fragments (sA never rewritten): 2 node-blocks of 16
    short8 af[2][2];
#pragma unroll
    for (int s = 0; s < 2; ++s)
#pragma unroll
        for (int q2 = 0; q2 < 2; ++q2)
            af[s][q2] = *(const short8*)(&sA[(s * 16 + lm) * 72 + q2 * 32 + quad * 8]);

    const float4v z4 = {0.f, 0.f, 0.f, 0.f};   // persistent MFMA C-init source

    // streaming pointers: W2q slices kk=2w,2w+1 (128B/lane each, adjacent blocks)
    const unsigned short* wp  = W2q + ((size_t)(kc * 512 + 2 * wave) * 64 + lane) * 64;
    const unsigned short* hbk = hB + kc * 512;   // + su*8 + voff per load

    // preload su = 0 (before the loop; no barrier in flight yet)
    short8 bf[2][4][2];
#pragma unroll
    for (int k2 = 0; k2 < 2; ++k2)
#pragma unroll
        for (int tt = 0; tt < 4; ++tt)
#pragma unroll
            for (int q2 = 0; q2 < 2; ++q2)
                bf[k2][tt][q2] = *(const short8*)(wp + k2 * 4096 + (tt * 2 + q2) * 8);
    wp += PANEL;
    unsigned hdA[MAXTW], hdB[MAXTW];
#pragma unroll
    for (int ai = 0; ai < MAXTW; ++ai) hdA[ai] = *(const unsigned*)(hbk + voff[ai]);

    int hoff = 8;   // short-offset of next su's hB columns (clamped at last su)

    auto subody = [&](unsigned (&HDc)[MAXTW], unsigned (&HDN)[MAXTW],
                      unsigned short* __restrict__ sYp) {
        // ---- phase 1: kk = 2w (a0) and 2w+1 (a1); write full units b128 ----
#pragma unroll
        for (int s = 0; s < 2; ++s) {
            float4v a0[4], a1[4];
#pragma unroll
            for (int tt = 0; tt < 4; ++tt)
                a0[tt] = __builtin_amdgcn_mfma_f32_16x16x32_bf16(af[s][0], bf[0][tt][0], z4, 0, 0, 0);
#pragma unroll
            for (int tt = 0; tt < 4; ++tt)
                a0[tt] = __builtin_amdgcn_mfma_f32_16x16x32_bf16(af[s][1], bf[0][tt][1], a0[tt], 0, 0, 0);
#pragma unroll
            for (int tt = 0; tt < 4; ++tt)
                a1[tt] = __builtin_amdgcn_mfma_f32_16x16x32_bf16(af[s][0], bf[1][tt][0], z4, 0, 0, 0);
#pragma unroll
            for (int tt = 0; tt < 4; ++tt)
                a1[tt] = __builtin_amdgcn_mfma_f32_16x16x32_bf16(af[s][1], bf[1][tt][1], a1[tt], 0, 0, 0);
#pragma unroll
            for (int tt = 0; tt < 4; ++tt) {
                uint4 v = make_uint4(pk2(a0[tt][0], a0[tt][1]), pk2(a0[tt][2], a0[tt][3]),
                                     pk2(a1[tt][0], a1[tt][1]), pk2(a1[tt][2], a1[tt][3]));
                *(uint4*)(&sYp[wb0 + s * 128 + tt * 4096]) = v;
            }
        }

        __syncthreads();   // the ONLY barrier per su: sY writes visible

        // ---- prefetch next su, issued strictly AFTER the barrier ----
#pragma unroll
        for (int k2 = 0; k2 < 2; ++k2)
#pragma unroll
            for (int tt = 0; tt < 4; ++tt)
#pragma unroll
                for (int q2 = 0; q2 < 2; ++q2)
                    bf[k2][tt][q2] = *(const short8*)(wp + k2 * 4096 + (tt * 2 + q2) * 8);
        wp += PANEL;
#pragma unroll
        for (int ai = 0; ai < MAXTW; ++ai)
            HDN[ai] = *(const unsigned*)(hbk + hoff + voff[ai]);
        hoff = (hoff < 504) ? hoff + 8 : 504;

        // ---- phase 2: per-tile MFMA from preloaded hd + sY ----
#pragma unroll
        for (int ai = 0; ai < MAXTW; ++ai) {
            if (wave + ai * 4 < ntiles) {                  // wave-uniform
                const unsigned h0 = HDc[ai];
                unsigned long long A = (unsigned long long)(h0 & 0xffffu) << shl5[ai];
                unsigned long long B = (unsigned long long)(h0 >> 16) << shl5[ai];
                uint4 aw = make_uint4((unsigned)A, (unsigned)(A >> 32),
                                      (unsigned)B, (unsigned)(B >> 32));
                short8 a2 = *(short8*)&aw;
#pragma unroll
                for (int ot = 0; ot < 4; ++ot) {
                    short8 b2f = *(const short8*)(&sYp[rbase[ai] + ot * 4096]);
                    acc2[ai][ot] = __builtin_amdgcn_mfma_f32_16x16x32_bf16(a2, b2f, acc2[ai][ot], 0, 0, 0);
                }
            }
        }
        // no trailing barrier: next phase 1 writes the other sY buffer
    };

    for (int su2 = 0; su2 < KSUBS; su2 += 2) {
        subody(hdA, hdB, sY);
        subody(hdB, hdA, sY + SYU);
    }

    // ---- flush: atomicAdd into agg[dst] ----
#pragma unroll
    for (int ai = 0; ai < MAXTW; ++ai) {
        const int ti = wave + ai * 4;
        if (ti < ntiles) {
#pragma unroll
            for (int r = 0; r < 4; ++r) {
                const int inf2 = __shfl(infoR[ai], quad * 4 + r, 64);
                if (inf2 >= 0) {
                    const int d = inf2 >> 16;
#pragma unroll
                    for (int ot = 0; ot < 4; ++ot)
                        atomicAdd(&agg[(size_t)d * 64 + ot * 16 + lm], acc2[ai][ot][r]);
                }
            }
        }
    }
}

// ---------------------------------------------------------------------------
// x_next = relu(agg/cnt + x @ root + bias)
// ---------------------------------------------------------------------------
__global__ void combine(const float* __restrict__ agg, const float* __restrict__ cnt,
                        const float* __restrict__ xcur, const float* __restrict__ root,
                        const float* __restrict__ bias, float* __restrict__ xn) {
    const int n = blockIdx.x * 4 + (threadIdx.x >> 6);
    const int o = threadIdx.x & 63;
    float a = agg[n * 64 + o] / fmaxf(cnt[n], 1.f);
    float r = bias[o];
#pragma unroll
    for (int i = 0; i < 64; ++i) r += xcur[n * 64 + i] * root[i * 64 + o];
    xn[n * 64 + o] = fmaxf(a + r, 0.f);
}

// ---------------------------------------------------------------------------
// global mean pool
// ---------------------------------------------------------------------------
__global__ void pool_accum(const float* __restrict__ x3, const int* __restrict__ batch,
                           float* __restrict__ pool, float* __restrict__ pcnt) {
    const int n = blockIdx.x * 4 + (threadIdx.x >> 6);
    const int o = threadIdx.x & 63;
    const int gi = batch[n];
    atomicAdd(&pool[gi * 64 + o], x3[n * 64 + o]);
    if (o == 0) atomicAdd(&pcnt[gi], 1.f);
}

__global__ void pool_norm(const float* __restrict__ pool, const float* __restrict__ pcnt,
                          float* __restrict__ out) {
    const int idx = blockIdx.x * 256 + threadIdx.x;
    out[idx] = pool[idx] / fmaxf(pcnt[idx >> 6], 1.f);
}

// ---------------------------------------------------------------------------
extern "C" void kernel_launch(void* const* d_in, const int* in_sizes, int n_in,
                              void* d_out, int out_size, void* d_ws, size_t ws_size,
                              hipStream_t stream) {
    const float* x   = (const float*)d_in[0];
    const int*   ei  = (const int*)d_in[1];
    const float* ea  = (const float*)d_in[2];
    const int*   bat = (const int*)d_in[3];
    const int* srcp = ei;
    const int* dstp = ei + EE;

    char* ws = (char*)d_ws;
    size_t off = 0;
    unsigned short* hB  = (unsigned short*)(ws + off); off += (size_t)(EE + 1) * HD * 2; // 128MB + zero row
    unsigned short* W2q = (unsigned short*)(ws + off); off += ((size_t)HD * HD + PANEL) * 2; // 32MB + pad
    int* slot_info      = (int*)(ws + off); off += (size_t)NGROUPS * MAXSLOT * 4;
    int* tile_cluster   = (int*)(ws + off); off += (size_t)NGROUPS * MAXT * 4;
    int* group_ntiles   = (int*)(ws + off); off += 1024;
    int* node_slot_base = (int*)(ws + off); off += (size_t)NN * 4;
    int* cnt_src        = (int*)(ws + off); off += (size_t)NN * 4;   // zeroed
    int* fillc          = (int*)(ws + off); off += (size_t)NN * 4;   // zeroed (contig)
    float* cnt_dst      = (float*)(ws + off); off += (size_t)NN * 4; // zeroed (contig)
    float* agg  = (float*)(ws + off); off += (size_t)NN * 64 * 4;
    float* xb   = (float*)(ws + off); off += (size_t)NN * 64 * 4;
    float* xb0  = (float*)(ws + off); off += (size_t)NN * 64 * 4;
    float* xb1  = (float*)(ws + off); off += (size_t)NN * 64 * 4;
    float* pool = (float*)(ws + off); off += (size_t)GG * 64 * 4;
    float* pcnt = (float*)(ws + off); off += (size_t)GG * 4;

    // ---- bucketing (edge structure fixed; rebuilt each call) ----
    hipMemsetAsync(slot_info, 0xFF, (size_t)NGROUPS * MAXSLOT * 4, stream);   // -1
    hipMemsetAsync(cnt_src, 0, (size_t)NN * 4 * 3, stream);                   // cnt_src+fill+cnt_dst
    hipMemsetAsync(hB + (size_t)EE * HD, 0, (size_t)HD * 2, stream);          // zero row for empty slots
    count_edges<<<EE / 256, 256, 0, stream>>>(srcp, dstp, cnt_src, cnt_dst);
    build_layout<<<1, 128, 0, stream>>>(cnt_src, node_slot_base, tile_cluster, group_ntiles);
    fill_slots<<<EE / 256, 256, 0, stream>>>(srcp, dstp, fillc, node_slot_base, slot_info);

    const float* xcur = x;
    float* xbufs[2] = {xb0, xb1};

    for (int l = 0; l < 3; ++l) {
        const float* w1   = (const float*)d_in[4 + 6 * l + 0];
        const float* b1   = (const float*)d_in[4 + 6 * l + 1];
        const float* w2   = (const float*)d_in[4 + 6 * l + 2];
        const float* b2   = (const float*)d_in[4 + 6 * l + 3];
        const float* root = (const float*)d_in[4 + 6 * l + 4];
        const float* bias = (const float*)d_in[4 + 6 * l + 5];

        wperm<<<HD, 256, 0, stream>>>(w2, W2q);
        hker<<<dim3(HD / 256, EE / 16), 256, 0, stream>>>(ea, w1, b1, hB);
        xb_ker<<<NN / 4, 256, 0, stream>>>(xcur, b2, xb);
        hipMemsetAsync(agg, 0, (size_t)NN * 64 * 4, stream);
        b2scatter<<<EE / 4, 256, 0, stream>>>(xb, srcp, dstp, agg);
        ygemm_msg<<<NGROUPS * GK, 256, 0, stream>>>(xcur, hB, W2q, slot_info,
                                                    tile_cluster, group_ntiles, agg);
        float* xn = xbufs[l & 1];
        combine<<<NN / 4, 256, 0, stream>>>(agg, cnt_dst, xcur, root, bias, xn);
        xcur = xn;
    }
    hipMemsetAsync(pool, 0, (size_t)GG * 64 * 4 + (size_t)GG * 4, stream); // pool+pcnt contiguous
    pool_accum<<<NN / 4, 256, 0, stream>>>(xcur, bat, pool, pcnt);
    pool_norm<<<GG * 64 / 256, 256, 0, stream>>>(pool, pcnt, (float*)d_out);
}

// Round 5
// 1620.700 us; speedup vs baseline: 1.3656x; 1.3656x over previous
//
#include <hip/hip_runtime.h>
#include <hip/hip_bf16.h>

// Problem constants (fixed by reference)
#define NN 4096      // nodes
#define EE 16384     // edges
#define GG 128       // graphs
#define EDIM 16      // edge_dim
#define HD 4096      // edge-MLP width = 64*64

// Factorized-algorithm tiling (R5: R0/R1 512-thread structure + raw barriers
// with LDS-only waits, distance-2 hB gather prefetch, additive XOR sY layout)
#define NGROUPS 64       // node groups (64 nodes each)
#define GK 8             // k-chunks (one 4MB W2q slice per XCD)
#define KSUBS 64         // 8-k sub-iterations per block
#define MAXT 40          // max 16-slot edge tiles per group
#define MAXSLOT (MAXT * 16)
#define MAXTW 5          // max tiles per wave
#define SYHALF (64 * 64 * 8)  // shorts per sY buffer (64 KB)
#define PANEL (8 * 64 * 64)   // W2q shorts per su (per-lane-contiguous layout)

typedef __attribute__((ext_vector_type(8))) short short8;
typedef __attribute__((ext_vector_type(4))) float float4v;

static __device__ inline unsigned short f2b(float f) {
    unsigned u = __float_as_uint(f);
    unsigned r = u + 0x7fff + ((u >> 16) & 1);   // RNE
    return (unsigned short)(r >> 16);
}

static __device__ inline unsigned pk2(float a, float b) {
    __hip_bfloat162 p = __float22bfloat162_rn(make_float2(a, b));
    return *(unsigned*)&p;
}

// ---------------------------------------------------------------------------
// h = relu(ea @ w1 + b1) -> bf16 [EE][HD]   (row EE of hB is a zero row,
// memset once per launch, used as the target of empty-slot gathers)
// ---------------------------------------------------------------------------
__global__ void hker(const float* __restrict__ ea, const float* __restrict__ w1,
                     const float* __restrict__ b1, unsigned short* __restrict__ hB) {
    __shared__ float sea[16 * 16];
    const int tid = threadIdx.x;
    const int j = blockIdx.x * 256 + tid;
    const int e0 = blockIdx.y * 16;
    float w[16];
#pragma unroll
    for (int k = 0; k < 16; ++k) w[k] = w1[k * HD + j];
    const float b = b1[j];
    sea[tid] = ea[e0 * EDIM + tid];
    __syncthreads();
#pragma unroll 4
    for (int el = 0; el < 16; ++el) {
        float a = b;
#pragma unroll
        for (int k = 0; k < 16; ++k) a += sea[el * 16 + k] * w[k];
        hB[(size_t)(e0 + el) * HD + j] = f2b(fmaxf(a, 0.f));
    }
}

// ---------------------------------------------------------------------------
// W2q permute, su-contiguous per (reader-wave, lane):
//   W2q[ ((ss*8 + kk)*64 + lane)*64 + (tt*2+q2)*8 + t ]
//     = bf16( w2[k*HD + (q2*32+quad*8+t)*64 + o] )   with k = ss*8+kk,
//       lane = quad*16+lm, o = tt*16+lm.
// Reader (ygemm wave kk, su ss) loads its 8 fragments from 128 contiguous
// bytes per lane with immediate offsets.
// ---------------------------------------------------------------------------
__global__ void wperm(const float* __restrict__ w2, unsigned short* __restrict__ W2q) {
    __shared__ float t[64 * 65];
    const int k = blockIdx.x;
    const int tid = threadIdx.x;
    const int o = tid & 63, r4 = tid >> 6;
#pragma unroll
    for (int it = 0; it < 16; ++it) {
        int i = it * 4 + r4;
        t[i * 65 + o] = w2[(size_t)k * HD + i * 64 + o];
    }
    __syncthreads();
    const int o2 = tid >> 2, q = tid & 3;
    const int q2 = q >> 1;
    const int j0 = (o2 >> 4) * 2 + q2;     // fragment slot j = tt*2+q2
    const int lmm = o2 & 15;
    const int blk = k;                      // = ss*8 + kk
#pragma unroll
    for (int cc = 0; cc < 2; ++cc) {
        const int quad = (q & 1) * 2 + cc;
        const int ib = q * 16 + cc * 8;     // i-base = q2*32 + quad*8
        size_t base = ((size_t)(blk * 64 + quad * 16 + lmm)) * 64 + j0 * 8;
        unsigned b0 = pk2(t[(ib + 0) * 65 + o2], t[(ib + 1) * 65 + o2]);
        unsigned b1 = pk2(t[(ib + 2) * 65 + o2], t[(ib + 3) * 65 + o2]);
        unsigned b2_ = pk2(t[(ib + 4) * 65 + o2], t[(ib + 5) * 65 + o2]);
        unsigned b3 = pk2(t[(ib + 6) * 65 + o2], t[(ib + 7) * 65 + o2]);
        *(uint4*)(&W2q[base]) = make_uint4(b0, b1, b2_, b3);
    }
}

// ---------------------------------------------------------------------------
// Edge bucketing (structure fixed per launch; rebuilt every call)
// ---------------------------------------------------------------------------
__global__ void count_edges(const int* __restrict__ src, const int* __restrict__ dst,
                            int* __restrict__ cnt_src, float* __restrict__ cnt_dst) {
    const int e = blockIdx.x * 256 + threadIdx.x;
    atomicAdd(&cnt_src[src[e]], 1);
    atomicAdd(&cnt_dst[dst[e]], 1.f);
}

__global__ void build_layout(const int* __restrict__ cnt_src, int* __restrict__ node_slot_base,
                             int* __restrict__ tile_cluster, int* __restrict__ group_ntiles) {
    const int g = threadIdx.x;        // 0..63, 64-node groups
    int nt = 0;
    int slot = g * MAXSLOT;
    for (int c = 0; c < 16; ++c) {    // 16 clusters of 4 nodes
        int d = 0;
        for (int j = 0; j < 4; ++j) {
            int n = g * 64 + c * 4 + j;
            node_slot_base[n] = slot + d;
            d += cnt_src[n];
        }
        int tcnt = (d + 15) >> 4;
        if (nt + tcnt > MAXT) tcnt = MAXT - nt;   // safety clamp
        for (int j = 0; j < tcnt; ++j) tile_cluster[g * MAXT + nt + j] = c;
        nt += tcnt;
        slot += tcnt * 16;
    }
    group_ntiles[g] = nt;
}

__global__ void fill_slots(const int* __restrict__ src, const int* __restrict__ dst,
                           int* __restrict__ fill, const int* __restrict__ node_slot_base,
                           int* __restrict__ slot_info) {
    const int e = blockIdx.x * 256 + threadIdx.x;
    const int n = src[e];
    const int pos = atomicAdd(&fill[n], 1);
    const int s = node_slot_base[n] + pos;
    const int g = n >> 6;             // 64 nodes/group
    if (s < g * MAXSLOT + MAXSLOT)
        slot_info[s] = e | ((n & 3) << 14) | (dst[e] << 16);
}

// ---------------------------------------------------------------------------
// xb[n,o] = sum_i x[n,i]*b2[i*64+o]; then scatter to agg (bias term of theta)
// ---------------------------------------------------------------------------
__global__ void xb_ker(const float* __restrict__ xcur, const float* __restrict__ b2,
                       float* __restrict__ xb) {
    const int n = blockIdx.x * 4 + (threadIdx.x >> 6);
    const int o = threadIdx.x & 63;
    float a = 0.f;
#pragma unroll
    for (int i = 0; i < 64; ++i) a += xcur[n * 64 + i] * b2[i * 64 + o];
    xb[n * 64 + o] = a;
}

__global__ void b2scatter(const float* __restrict__ xb, const int* __restrict__ src,
                          const int* __restrict__ dst, float* __restrict__ agg) {
    const int e = blockIdx.x * 4 + (threadIdx.x >> 6);
    const int o = threadIdx.x & 63;
    atomicAdd(&agg[(size_t)dst[e] * 64 + o], xb[(size_t)src[e] * 64 + o]);
}

// ---------------------------------------------------------------------------
// Fused factorized kernel — 8-wave blocks, 64-node groups, 1 block/CU.
//   Per su: phase1 (y-panel, kk = wave) -> RAW barrier (LDS-only wait) ->
//   W2q reload (su+1) -> phase2 (h·y MFMA) -> hB gather issue (su+2).
//   The raw barrier (s_waitcnt lgkmcnt(0); s_barrier) does NOT drain vmcnt,
//   so W2q/hB prefetches stay in flight across barriers and are waited with
//   compiler-counted vmcnt(N) at first use (T4). hB gather runs at
//   distance 2 (~1.5 su lead >> HBM latency).
//   sY layout: unit U(clqg,o) = o*64 + (clqg ^ (o&7)) -> write addr
//   tt*8192 + s*128 + per-lane base (all-immediate offsets, conflict-free
//   8-lane-per-bank-group on both uint2 writes and b128 reads).
// ---------------------------------------------------------------------------
__global__ __launch_bounds__(512, 2)
void ygemm_msg(const float* __restrict__ xcur, const unsigned short* __restrict__ hB,
               const unsigned short* __restrict__ W2q, const int* __restrict__ slot_info,
               const int* __restrict__ tile_cluster, const int* __restrict__ group_ntiles,
               float* __restrict__ agg) {
    __shared__ __align__(16) unsigned short sA[64 * 72];        // 9 KB
    __shared__ __align__(16) unsigned short sY[2 * SYHALF];     // 128 KB double buffer

    const int bid = blockIdx.x;
    const int g = bid >> 3;
    const int kc = bid & 7;
    const int tid = threadIdx.x;
    const int lane = tid & 63, wave = tid >> 6;    // wave 0..7 (= kk)
    const int quad = lane >> 4, lm = lane & 15;

    // stage x group (64 nodes x 64 i) as bf16
    {
        const int n = tid >> 3, ib = (tid & 7) * 8;
        const float* xp = xcur + (size_t)(g * 64 + n) * 64 + ib;
        uint4 w = make_uint4(pk2(xp[0], xp[1]), pk2(xp[2], xp[3]),
                             pk2(xp[4], xp[5]), pk2(xp[6], xp[7]));
        *(uint4*)(&sA[n * 72 + ib]) = w;
    }

    const int ntiles = group_ntiles[g];
    // Per-tile su-invariant precompute: slot info, gather voffset (empty slots
    // -> zero row EE), sY read base (XOR layout), unpack shift (nl*16).
    int infoR[MAXTW], voff[MAXTW], rbase[MAXTW];
    unsigned shl5[MAXTW];
#pragma unroll
    for (int ai = 0; ai < MAXTW; ++ai) {
        const int ti = wave + ai * 8;
        const int info = (ti < ntiles) ? slot_info[g * MAXSLOT + ti * 16 + lm] : -1;
        const int tc   = (ti < ntiles) ? tile_cluster[g * MAXT + ti] : 0;
        infoR[ai] = info;
        voff[ai]  = ((info >= 0) ? (info & 0x3FFF) : EE) * HD + quad * 2;
        rbase[ai] = lm * 512 + (((tc * 4 + quad) ^ (lm & 7)) << 3);
        shl5[ai]  = (unsigned)(((info >> 14) & 3) * 16);
    }

    float4v acc2[MAXTW][4];
#pragma unroll
    for (int a = 0; a < MAXTW; ++a)
#pragma unroll
        for (int t = 0; t < 4; ++t) {
            acc2[a][t][0] = 0.f; acc2[a][t][1] = 0.f;
            acc2[a][t][2] = 0.f; acc2[a][t][3] = 0.f;
        }

    const int qg = wave >> 1, half = wave & 1;
    // phase-1 write base (shorts); s*128 and tt*8192 are immediate offsets
    const int wb = lm * 512 + (((quad * 4 + qg) ^ (lm & 7)) << 3) + half * 4;
    __syncthreads();

    // loop-invariant A-fragments (sA never rewritten)
    short8 af[4][2];
#pragma unroll
    for (int s = 0; s < 4; ++s)
#pragma unroll
        for (int q2 = 0; q2 < 2; ++q2)
            af[s][q2] = *(const short8*)(&sA[(s * 16 + lm) * 72 + q2 * 32 + quad * 8]);

    const float4v z4 = {0.f, 0.f, 0.f, 0.f};   // persistent MFMA C-init source

    // streaming pointers: W2q per-lane-contiguous (advance 1 panel/su),
    // hB uniform base (per-lane part lives in voff)
    const unsigned short* wp  = W2q + ((size_t)(kc * KSUBS * 8 + wave) * 64 + lane) * 64;
    const unsigned short* hbk = hB + kc * KSUBS * 8;

    // preload su=0 W2q fragments; su=0 and su=1 hB gathers
    short8 BF[4][2];
#pragma unroll
    for (int tt = 0; tt < 4; ++tt) {
        BF[tt][0] = *(const short8*)(wp + (tt * 2 + 0) * 8);
        BF[tt][1] = *(const short8*)(wp + (tt * 2 + 1) * 8);
    }
    wp += PANEL;
    unsigned hdA[MAXTW], hdB[MAXTW];
#pragma unroll
    for (int ai = 0; ai < MAXTW; ++ai) {
        hdA[ai] = *(const unsigned*)(hbk + voff[ai]);
        hdB[ai] = *(const unsigned*)(hbk + 8 + voff[ai]);
    }

    int hoff = 16;   // short-offset of su+2's hB columns (clamped at the end)

    auto subody = [&](unsigned (&HDc)[MAXTW], unsigned short* __restrict__ sYp) {
        // ---- phase 1: y panel (kk = wave), s-sequential to cap registers ----
#pragma unroll
        for (int s = 0; s < 4; ++s) {
            float4v a1[4];
#pragma unroll
            for (int tt = 0; tt < 4; ++tt)
                a1[tt] = __builtin_amdgcn_mfma_f32_16x16x32_bf16(af[s][0], BF[tt][0], z4, 0, 0, 0);
#pragma unroll
            for (int tt = 0; tt < 4; ++tt)
                a1[tt] = __builtin_amdgcn_mfma_f32_16x16x32_bf16(af[s][1], BF[tt][1], a1[tt], 0, 0, 0);
#pragma unroll
            for (int tt = 0; tt < 4; ++tt) {
                uint2 v;
                v.x = pk2(a1[tt][0], a1[tt][1]);
                v.y = pk2(a1[tt][2], a1[tt][3]);
                *(uint2*)(&sYp[wb + s * 128 + tt * 8192]) = v;
            }
        }

        // RAW barrier: wait only for LDS ops (sY writes); global prefetches
        // stay in flight across the barrier (counted vmcnt at their uses).
        asm volatile("s_waitcnt lgkmcnt(0)" ::: "memory");
        __builtin_amdgcn_s_barrier();

        // ---- W2q fragment reload for su+1 (L2-resident; lead = phase 2) ----
#pragma unroll
        for (int tt = 0; tt < 4; ++tt) {
            BF[tt][0] = *(const short8*)(wp + (tt * 2 + 0) * 8);
            BF[tt][1] = *(const short8*)(wp + (tt * 2 + 1) * 8);
        }
        wp += PANEL;

        // ---- phase 2: per-tile MFMA from preloaded hd + sY ----
#pragma unroll
        for (int ai = 0; ai < MAXTW; ++ai) {
            if (wave + ai * 8 < ntiles) {                  // wave-uniform
                const unsigned h0 = HDc[ai];
                // place (lo,hi) bf16 pair at halfword nl via 64-bit shifts
                unsigned long long A = (unsigned long long)(h0 & 0xffffu) << shl5[ai];
                unsigned long long B = (unsigned long long)(h0 >> 16) << shl5[ai];
                uint4 aw = make_uint4((unsigned)A, (unsigned)(A >> 32),
                                      (unsigned)B, (unsigned)(B >> 32));
                short8 a2 = *(short8*)&aw;
#pragma unroll
                for (int ot = 0; ot < 4; ++ot) {
                    short8 b2f = *(const short8*)(&sYp[rbase[ai] + ot * 8192]);
                    acc2[ai][ot] = __builtin_amdgcn_mfma_f32_16x16x32_bf16(a2, b2f, acc2[ai][ot], 0, 0, 0);
                }
            }
        }

        // ---- hB gather for su+2 into the just-consumed slot (distance 2,
        //      ~1.5 su of lead >> HBM latency) ----
#pragma unroll
        for (int ai = 0; ai < MAXTW; ++ai)
            HDc[ai] = *(const unsigned*)(hbk + hoff + voff[ai]);
        hoff = (hoff < 504) ? hoff + 8 : 504;
        // no trailing barrier: next phase 1 writes the other sY buffer
    };

    for (int su2 = 0; su2 < KSUBS; su2 += 2) {
        subody(hdA, sY);
        subody(hdB, sY + SYHALF);
    }

    // ---- flush: atomicAdd into agg[dst] ----
#pragma unroll
    for (int ai = 0; ai < MAXTW; ++ai) {
        const int ti = wave + ai * 8;
        if (ti < ntiles) {
#pragma unroll
            for (int r = 0; r < 4; ++r) {
                const int inf2 = __shfl(infoR[ai], quad * 4 + r, 64);
                if (inf2 >= 0) {
                    const int d = inf2 >> 16;
#pragma unroll
                    for (int ot = 0; ot < 4; ++ot)
                        atomicAdd(&agg[(size_t)d * 64 + ot * 16 + lm], acc2[ai][ot][r]);
                }
            }
        }
    }
}

// ---------------------------------------------------------------------------
// x_next = relu(agg/cnt + x @ root + bias)
// ---------------------------------------------------------------------------
__global__ void combine(const float* __restrict__ agg, const float* __restrict__ cnt,
                        const float* __restrict__ xcur, const float* __restrict__ root,
                        const float* __restrict__ bias, float* __restrict__ xn) {
    const int n = blockIdx.x * 4 + (threadIdx.x >> 6);
    const int o = threadIdx.x & 63;
    float a = agg[n * 64 + o] / fmaxf(cnt[n], 1.f);
    float r = bias[o];
#pragma unroll
    for (int i = 0; i < 64; ++i) r += xcur[n * 64 + i] * root[i * 64 + o];
    xn[n * 64 + o] = fmaxf(a + r, 0.f);
}

// ---------------------------------------------------------------------------
// global mean pool
// ---------------------------------------------------------------------------
__global__ void pool_accum(const float* __restrict__ x3, const int* __restrict__ batch,
                           float* __restrict__ pool, float* __restrict__ pcnt) {
    const int n = blockIdx.x * 4 + (threadIdx.x >> 6);
    const int o = threadIdx.x & 63;
    const int gi = batch[n];
    atomicAdd(&pool[gi * 64 + o], x3[n * 64 + o]);
    if (o == 0) atomicAdd(&pcnt[gi], 1.f);
}

__global__ void pool_norm(const float* __restrict__ pool, const float* __restrict__ pcnt,
                          float* __restrict__ out) {
    const int idx = blockIdx.x * 256 + threadIdx.x;
    out[idx] = pool[idx] / fmaxf(pcnt[idx >> 6], 1.f);
}

// ---------------------------------------------------------------------------
extern "C" void kernel_launch(void* const* d_in, const int* in_sizes, int n_in,
                              void* d_out, int out_size, void* d_ws, size_t ws_size,
                              hipStream_t stream) {
    const float* x   = (const float*)d_in[0];
    const int*   ei  = (const int*)d_in[1];
    const float* ea  = (const float*)d_in[2];
    const int*   bat = (const int*)d_in[3];
    const int* srcp = ei;
    const int* dstp = ei + EE;

    char* ws = (char*)d_ws;
    size_t off = 0;
    unsigned short* hB  = (unsigned short*)(ws + off); off += (size_t)(EE + 1) * HD * 2; // 128MB + zero row
    unsigned short* W2q = (unsigned short*)(ws + off); off += ((size_t)HD * HD + PANEL) * 2; // 32MB + pad
    int* slot_info      = (int*)(ws + off); off += (size_t)NGROUPS * MAXSLOT * 4;
    int* tile_cluster   = (int*)(ws + off); off += (size_t)NGROUPS * MAXT * 4;
    int* group_ntiles   = (int*)(ws + off); off += 1024;
    int* node_slot_base = (int*)(ws + off); off += (size_t)NN * 4;
    int* cnt_src        = (int*)(ws + off); off += (size_t)NN * 4;   // zeroed
    int* fillc          = (int*)(ws + off); off += (size_t)NN * 4;   // zeroed (contig)
    float* cnt_dst      = (float*)(ws + off); off += (size_t)NN * 4; // zeroed (contig)
    float* agg  = (float*)(ws + off); off += (size_t)NN * 64 * 4;
    float* xb   = (float*)(ws + off); off += (size_t)NN * 64 * 4;
    float* xb0  = (float*)(ws + off); off += (size_t)NN * 64 * 4;
    float* xb1  = (float*)(ws + off); off += (size_t)NN * 64 * 4;
    float* pool = (float*)(ws + off); off += (size_t)GG * 64 * 4;
    float* pcnt = (float*)(ws + off); off += (size_t)GG * 4;

    // ---- bucketing (edge structure fixed; rebuilt each call) ----
    hipMemsetAsync(slot_info, 0xFF, (size_t)NGROUPS * MAXSLOT * 4, stream);   // -1
    hipMemsetAsync(cnt_src, 0, (size_t)NN * 4 * 3, stream);                   // cnt_src+fill+cnt_dst
    hipMemsetAsync(hB + (size_t)EE * HD, 0, (size_t)HD * 2, stream);          // zero row for empty slots
    count_edges<<<EE / 256, 256, 0, stream>>>(srcp, dstp, cnt_src, cnt_dst);
    build_layout<<<1, 64, 0, stream>>>(cnt_src, node_slot_base, tile_cluster, group_ntiles);
    fill_slots<<<EE / 256, 256, 0, stream>>>(srcp, dstp, fillc, node_slot_base, slot_info);

    const float* xcur = x;
    float* xbufs[2] = {xb0, xb1};

    for (int l = 0; l < 3; ++l) {
        const float* w1   = (const float*)d_in[4 + 6 * l + 0];
        const float* b1   = (const float*)d_in[4 + 6 * l + 1];
        const float* w2   = (const float*)d_in[4 + 6 * l + 2];
        const float* b2   = (const float*)d_in[4 + 6 * l + 3];
        const float* root = (const float*)d_in[4 + 6 * l + 4];
        const float* bias = (const float*)d_in[4 + 6 * l + 5];

        wperm<<<HD, 256, 0, stream>>>(w2, W2q);
        hker<<<dim3(HD / 256, EE / 16), 256, 0, stream>>>(ea, w1, b1, hB);
        xb_ker<<<NN / 4, 256, 0, stream>>>(xcur, b2, xb);
        hipMemsetAsync(agg, 0, (size_t)NN * 64 * 4, stream);
        b2scatter<<<EE / 4, 256, 0, stream>>>(xb, srcp, dstp, agg);
        ygemm_msg<<<NGROUPS * GK, 512, 0, stream>>>(xcur, hB, W2q, slot_info,
                                                    tile_cluster, group_ntiles, agg);
        float* xn = xbufs[l & 1];
        combine<<<NN / 4, 256, 0, stream>>>(agg, cnt_dst, xcur, root, bias, xn);
        xcur = xn;
    }
    hipMemsetAsync(pool, 0, (size_t)GG * 64 * 4 + (size_t)GG * 4, stream); // pool+pcnt contiguous
    pool_accum<<<NN / 4, 256, 0, stream>>>(xcur, bat, pool, pcnt);
    pool_norm<<<GG * 64 / 256, 256, 0, stream>>>(pool, pcnt, (float*)d_out);
}